// Round 4
// baseline (132.433 us; speedup 1.0000x reference)
//
#include <hip/hip_runtime.h>
#include <stdint.h>

// SDF closest-point + signed distance, 8192 queries x 2048 tris.
//
// Correctness model (R1-R3 triangulation): harness ref = numpy float32
// faithful execution of the reference chain (strict IEEE f32, NO fma, no
// FTZ, sequential 3-elem sums, np.argmin first-occurrence). R1 failed only
// because HIP's __f*_rn intrinsics are plain ops that hipcc's default
// -ffp-contract=fast-honor-pragmas fused into FMAs, perturbing d2 by ulps
// and flipping a near-tie argmin (sign flip -> 0.31). R2/R3 (f64) flipped
// the same f32-exact tie via sub-ulp ordering. Fix: f32 everywhere with
// `#pragma clang fp contract(off)` INSIDE every function (honored by
// fast-honor-pragmas), plain IEEE ops, first-occurrence argmin on f32 d2.

__device__ __forceinline__ float safe32(float x) {
    return (fabsf(x) < 1e-12f) ? 1e-12f : x;
}

// Ericson closest-point, strict f32, numpy op order, region priority
// a > b > ab > c > ac > bc > interior (reference where-chain).
__device__ __forceinline__ float closest_point32(
    float px, float py, float pz,
    float ax, float ay, float az,
    float bx, float by, float bz,
    float cx, float cy, float cz,
    float& rx, float& ry, float& rz)
{
#pragma clang fp contract(off)
    float abx = bx - ax, aby = by - ay, abz = bz - az;
    float acx = cx - ax, acy = cy - ay, acz = cz - az;
    float cbx = cx - bx, cby = cy - by, cbz = cz - bz;

    float apx = px - ax, apy = py - ay, apz = pz - az;
    float bpx = px - bx, bpy = py - by, bpz = pz - bz;
    float qpx = px - cx, qpy = py - cy, qpz = pz - cz;

    float d1 = ((abx * apx) + (aby * apy)) + (abz * apz);
    float d2 = ((acx * apx) + (acy * apy)) + (acz * apz);
    float d3 = ((abx * bpx) + (aby * bpy)) + (abz * bpz);
    float d4 = ((acx * bpx) + (acy * bpy)) + (acz * bpz);
    float d5 = ((abx * qpx) + (aby * qpy)) + (abz * qpz);
    float d6 = ((acx * qpx) + (acy * qpy)) + (acz * qpz);

    float vc = (d1 * d4) - (d3 * d2);
    float vb = (d5 * d2) - (d1 * d6);
    float va = (d3 * d6) - (d5 * d4);
    float e1 = d4 - d3;
    float e2 = d5 - d6;

    bool ca  = (d1 <= 0.0f) && (d2 <= 0.0f);
    bool cb2 = (d3 >= 0.0f) && (d4 <= d3);
    bool cab = (vc <= 0.0f) && (d1 >= 0.0f) && (d3 <= 0.0f);
    bool cc  = (d6 >= 0.0f) && (d5 <= d6);
    bool cac = (vb <= 0.0f) && (d2 >= 0.0f) && (d6 <= 0.0f);
    bool cbc = (va <= 0.0f) && (e1 >= 0.0f) && (e2 >= 0.0f);

    int region = 6;            // interior
    if (cbc) region = 5;
    if (cac) region = 4;
    if (cc)  region = 3;
    if (cab) region = 2;
    if (cb2) region = 1;
    if (ca)  region = 0;

    float denom = safe32((va + vb) + vc);

    float num1 = 0.0f, den1 = 1.0f;
    if (region == 2) { num1 = d1; den1 = safe32(d1 - d3); }
    if (region == 4) { num1 = d2; den1 = safe32(d2 - d6); }
    if (region == 5) { num1 = e1; den1 = safe32(e1 + e2); }
    if (region == 6) { num1 = vb; den1 = denom; }
    float num2 = (region == 6) ? vc : 0.0f;
    float q1 = num1 / den1;          // IEEE f32 divide (no fast-math)
    float q2 = num2 / denom;

    float basx = ax, basy = ay, basz = az;
    if (region == 1 || region == 5) { basx = bx; basy = by; basz = bz; }
    if (region == 3)                { basx = cx; basy = cy; basz = cz; }

    float t1x = 0.0f, t1y = 0.0f, t1z = 0.0f;
    if (region == 2 || region == 6) { t1x = abx; t1y = aby; t1z = abz; }
    if (region == 4)                { t1x = acx; t1y = acy; t1z = acz; }
    if (region == 5)                { t1x = cbx; t1y = cby; t1z = cbz; }

    float t2x = (region == 6) ? acx : 0.0f;
    float t2y = (region == 6) ? acy : 0.0f;
    float t2z = (region == 6) ? acz : 0.0f;

    rx = (basx + (t1x * q1)) + (t2x * q2);
    ry = (basy + (t1y * q1)) + (t2y * q2);
    rz = (basz + (t1z * q1)) + (t2z * q2);

    float dx = px - rx, dy = py - ry, dz = pz - rz;
    return ((dx * dx) + (dy * dy)) + (dz * dz);
}

// Gather faces -> packed triangle array [nF][9] f32.
__global__ void k_prep(const int* __restrict__ faces, const float* __restrict__ verts,
                       float* __restrict__ tris, int nF)
{
    int i = blockIdx.x * 256 + threadIdx.x;
    if (i < nF) {
        int i0 = faces[i * 3 + 0], i1 = faces[i * 3 + 1], i2 = faces[i * 3 + 2];
        float* t = &tris[i * 9];
        t[0] = verts[i0 * 3]; t[1] = verts[i0 * 3 + 1]; t[2] = verts[i0 * 3 + 2];
        t[3] = verts[i1 * 3]; t[4] = verts[i1 * 3 + 1]; t[5] = verts[i1 * 3 + 2];
        t[6] = verts[i2 * 3]; t[7] = verts[i2 * 3 + 1]; t[8] = verts[i2 * 3 + 2];
    }
}

// One wave per query. Lanes stride faces; strict-f32 (d2, idx) lexicographic
// wave-min == np.argmin(float32 d2) first-occurrence, bit-exact.
__global__ __launch_bounds__(256) void k_main(
    const float* __restrict__ tris, const float* __restrict__ query,
    float* __restrict__ out, int nF, int nQ)
{
#pragma clang fp contract(off)
    const int gtid = blockIdx.x * 256 + threadIdx.x;
    const int q = gtid >> 6;          // wave id = query id
    const int lane = threadIdx.x & 63;
    if (q >= nQ) return;

    const float px = query[q * 3];
    const float py = query[q * 3 + 1];
    const float pz = query[q * 3 + 2];

    float best = 3.402823466e38f;
    int bidx = 0x7fffffff;
    for (int f = lane; f < nF; f += 64) {
        const float* t = &tris[f * 9];
        float rx, ry, rz;
        float d2 = closest_point32(px, py, pz,
            t[0], t[1], t[2], t[3], t[4], t[5], t[6], t[7], t[8],
            rx, ry, rz);
        // f increases within a lane: strict < keeps first occurrence
        if (d2 < best) { best = d2; bidx = f; }
    }

    // lexicographic (d2, idx) wave reduction -> lane 0 holds global argmin
    for (int off = 32; off > 0; off >>= 1) {
        float od = __shfl_down(best, off);
        int   oi = __shfl_down(bidx, off);
        if (od < best || (od == best && oi < bidx)) { best = od; bidx = oi; }
    }

    if (lane == 0) {
        const float* t = &tris[bidx * 9];
        float ax = t[0], ay = t[1], az = t[2];
        float bx = t[3], by = t[4], bz = t[5];
        float cx = t[6], cy = t[7], cz = t[8];

        float rx, ry, rz;
        closest_point32(px, py, pz, ax, ay, az, bx, by, bz, cx, cy, cz,
                        rx, ry, rz);

        // n = cross(b-a, c-a), numpy order
        float abx = bx - ax, aby = by - ay, abz = bz - az;
        float acx = cx - ax, acy = cy - ay, acz = cz - az;
        float nx = (aby * acz) - (abz * acy);
        float ny = (abz * acx) - (abx * acz);
        float nz = (abx * acy) - (aby * acx);

        float dx = px - rx, dy = py - ry, dz = pz - rz;
        float sdot = ((dx * nx) + (dy * ny)) + (dz * nz);
        float sgn = (sdot >= 0.0f) ? 1.0f : -1.0f;
        float sdist = sgn * __fsqrt_rn(fmaxf(best, 0.0f));

        out[q * 4 + 0] = rx;
        out[q * 4 + 1] = ry;
        out[q * 4 + 2] = rz;
        out[q * 4 + 3] = sdist;
    }
}

extern "C" void kernel_launch(void* const* d_in, const int* in_sizes, int n_in,
                              void* d_out, int out_size, void* d_ws, size_t ws_size,
                              hipStream_t stream) {
    const int* faces = (const int*)d_in[0];
    const float* verts = (const float*)d_in[1];
    const float* query = (const float*)d_in[2];
    float* out = (float*)d_out;

    const int nF = in_sizes[0] / 3;
    const int nQ = in_sizes[2] / 3;

    float* tris = (float*)d_ws;

    k_prep<<<(nF + 255) / 256, 256, 0, stream>>>(faces, verts, tris, nF);

    int blocks = (nQ * 64 + 255) / 256;   // one 64-lane wave per query
    k_main<<<blocks, 256, 0, stream>>>(tris, query, out, nF, nQ);
}

// Round 5
// 127.191 us; speedup vs baseline: 1.0412x; 1.0412x over previous
//
#include <hip/hip_runtime.h>
#include <stdint.h>

// SDF closest-point + signed distance, 8192 queries x 2048 tris.
//
// Correctness model (verified R4): harness ref = numpy float32 faithful chain.
// Requirements: strict IEEE f32, NO fma contraction (pragma inside every
// function body), numpy op order, np.argmin first-occurrence on f32 d2.
//
// R5 structure: query-per-thread, 64-face chunks staged in LDS (wave-uniform
// broadcast ds_read_b128), per-face data precomputed once (a,b,c,ab,ac,cb),
// priority-mask cndmask selects, u64 atomicMin (d2bits<<32|idx) merge ==
// lexicographic (d2, idx) min == np.argmin first occurrence.

#define QPB 256   // queries per block (threads)
#define FC  64    // faces per chunk staged in LDS
#define RECF 20   // floats per face record (18 + pad to 5x float4)

__device__ __forceinline__ float safe32(float x) {
    return (fabsf(x) < 1e-12f) ? 1e-12f : x;
}

// Strict-f32 Ericson closest point. rec = 5x float4: a3 b3 c3 ab3 ac3 cb3 pad2.
// Returns d2; writes closest point to rx,ry,rz. Bit-identical to the numpy
// reference chain for the selected region (selection via exclusive masks).
__device__ __forceinline__ float cp32(
    float px, float py, float pz, const float4* __restrict__ rec,
    float& rx, float& ry, float& rz)
{
#pragma clang fp contract(off)
    float4 r0 = rec[0], r1 = rec[1], r2 = rec[2], r3 = rec[3], r4 = rec[4];
    float ax = r0.x, ay = r0.y, az = r0.z, bx = r0.w;
    float by = r1.x, bz = r1.y, cx = r1.z, cy = r1.w;
    float cz = r2.x, abx = r2.y, aby = r2.z, abz = r2.w;
    float acx = r3.x, acy = r3.y, acz = r3.z, cbx = r3.w;
    float cby = r4.x, cbz = r4.y;

    float apx = px - ax, apy = py - ay, apz = pz - az;
    float bpx = px - bx, bpy = py - by, bpz = pz - bz;
    float qpx = px - cx, qpy = py - cy, qpz = pz - cz;

    float d1 = ((abx * apx) + (aby * apy)) + (abz * apz);
    float d2 = ((acx * apx) + (acy * apy)) + (acz * apz);
    float d3 = ((abx * bpx) + (aby * bpy)) + (abz * bpz);
    float d4 = ((acx * bpx) + (acy * bpy)) + (acz * bpz);
    float d5 = ((abx * qpx) + (aby * qpy)) + (abz * qpz);
    float d6 = ((acx * qpx) + (acy * qpy)) + (acz * qpz);

    float vc = (d1 * d4) - (d3 * d2);
    float vb = (d5 * d2) - (d1 * d6);
    float va = (d3 * d6) - (d5 * d4);
    float e1 = d4 - d3;
    float e2 = d5 - d6;

    bool ca  = (d1 <= 0.0f) && (d2 <= 0.0f);
    bool cb_ = (d3 >= 0.0f) && (d4 <= d3);
    bool cab = (vc <= 0.0f) && (d1 >= 0.0f) && (d3 <= 0.0f);
    bool cc  = (d6 >= 0.0f) && (d5 <= d6);
    bool cac = (vb <= 0.0f) && (d2 >= 0.0f) && (d6 <= 0.0f);
    bool cbc = (va <= 0.0f) && (e1 >= 0.0f) && (e2 >= 0.0f);

    // priority a > b > ab > c > ac > bc > interior; exclusive masks (SALU)
    bool tk  = ca;
    bool m_b  = cb_ && !tk;  tk = tk || cb_;
    bool m_ab = cab && !tk;  tk = tk || cab;
    bool m_c  = cc  && !tk;  tk = tk || cc;
    bool m_ac = cac && !tk;  tk = tk || cac;
    bool m_bc = cbc && !tk;  tk = tk || cbc;
    bool m_in = !tk;

    float denom_raw = (va + vb) + vc;
    float num1 = m_ab ? d1 : m_ac ? d2 : m_bc ? e1 : m_in ? vb : 0.0f;
    float den1_raw = m_ab ? (d1 - d3) : m_ac ? (d2 - d6)
                   : m_bc ? (e1 + e2) : m_in ? denom_raw : 1.0f;
    float den1  = safe32(den1_raw);
    float denom = safe32(denom_raw);
    float num2  = m_in ? vc : 0.0f;
    float q1 = num1 / den1;    // IEEE f32 divide
    float q2 = num2 / denom;

    bool sel_b = m_b || m_bc;
    float basx = m_c ? cx : sel_b ? bx : ax;
    float basy = m_c ? cy : sel_b ? by : ay;
    float basz = m_c ? cz : sel_b ? bz : az;

    bool s_ab = m_ab || m_in;
    float t1x = m_bc ? cbx : m_ac ? acx : s_ab ? abx : 0.0f;
    float t1y = m_bc ? cby : m_ac ? acy : s_ab ? aby : 0.0f;
    float t1z = m_bc ? cbz : m_ac ? acz : s_ab ? abz : 0.0f;

    float t2x = m_in ? acx : 0.0f;
    float t2y = m_in ? acy : 0.0f;
    float t2z = m_in ? acz : 0.0f;

    rx = (basx + (t1x * q1)) + (t2x * q2);
    ry = (basy + (t1y * q1)) + (t2y * q2);
    rz = (basz + (t1z * q1)) + (t2z * q2);

    float dx = px - rx, dy = py - ry, dz = pz - rz;
    return ((dx * dx) + (dy * dy)) + (dz * dz);
}

// Gather faces -> 20-float records (a,b,c,ab,ac,cb,pad2); init argmin keys.
__global__ void k_prep(const int* __restrict__ faces, const float* __restrict__ verts,
                       float* __restrict__ tris, unsigned long long* __restrict__ keys,
                       int nF, int nQ)
{
#pragma clang fp contract(off)
    int i = blockIdx.x * 256 + threadIdx.x;
    if (i < nQ) keys[i] = 0xffffffffffffffffULL;
    if (i < nF) {
        int i0 = faces[i * 3 + 0], i1 = faces[i * 3 + 1], i2 = faces[i * 3 + 2];
        float ax = verts[i0 * 3], ay = verts[i0 * 3 + 1], az = verts[i0 * 3 + 2];
        float bx = verts[i1 * 3], by = verts[i1 * 3 + 1], bz = verts[i1 * 3 + 2];
        float cx = verts[i2 * 3], cy = verts[i2 * 3 + 1], cz = verts[i2 * 3 + 2];
        float* t = &tris[i * RECF];
        t[0]  = ax; t[1]  = ay; t[2]  = az; t[3]  = bx;
        t[4]  = by; t[5]  = bz; t[6]  = cx; t[7]  = cy;
        t[8]  = cz;
        t[9]  = bx - ax; t[10] = by - ay; t[11] = bz - az;   // ab
        t[12] = cx - ax; t[13] = cy - ay; t[14] = cz - az;   // ac
        t[15] = cx - bx; t[16] = cy - by; t[17] = cz - bz;   // cb
        t[18] = 0.0f; t[19] = 0.0f;
    }
}

// Main: block = 256 queries x 64-face chunk (LDS broadcast). One u64
// atomicMin per (query, chunk) merges exact (d2, idx) lexicographic min.
__global__ __launch_bounds__(QPB) void k_main(
    const float* __restrict__ tris, const float* __restrict__ query,
    unsigned long long* __restrict__ keys, int nF, int nQ)
{
    __shared__ float4 s4[FC * (RECF / 4)];
    const int fbase = blockIdx.y * FC;
    const int nf = min(FC, nF - fbase);
    const int tid = threadIdx.x;

    {   // stage chunk: coalesced float4 copies
        const float4* src = (const float4*)&tris[(size_t)fbase * RECF];
        for (int i = tid; i < nf * (RECF / 4); i += QPB) s4[i] = src[i];
    }
    __syncthreads();

    const int q = blockIdx.x * QPB + tid;
    if (q >= nQ) return;
    const float px = query[q * 3], py = query[q * 3 + 1], pz = query[q * 3 + 2];

    float best = 3.402823466e38f;
    int bidx = 0x7fffffff;
    for (int f = 0; f < nf; ++f) {
        float rx, ry, rz;
        float d2 = cp32(px, py, pz, &s4[f * (RECF / 4)], rx, ry, rz);
        // f ascends: strict < keeps lowest index on exact ties
        if (d2 < best) { best = d2; bidx = fbase + f; }
    }
    unsigned long long key =
        ((unsigned long long)__float_as_uint(best) << 32) | (unsigned)bidx;
    atomicMin(&keys[q], key);
}

// Finalize: decode winner, recompute cp (identical bits), normal, sign.
__global__ void k_final(const float* __restrict__ tris, const float* __restrict__ query,
                        const unsigned long long* __restrict__ keys,
                        float* __restrict__ out, int nQ)
{
#pragma clang fp contract(off)
    int q = blockIdx.x * 256 + threadIdx.x;
    if (q >= nQ) return;
    unsigned long long key = keys[q];
    unsigned idx = (unsigned)(key & 0xffffffffu);
    float best_d2 = __uint_as_float((unsigned)(key >> 32));

    const float px = query[q * 3], py = query[q * 3 + 1], pz = query[q * 3 + 2];
    const float4* rec = (const float4*)&tris[(size_t)idx * RECF];
    float rx, ry, rz;
    cp32(px, py, pz, rec, rx, ry, rz);

    // n = cross(ab, ac), numpy order; ab/ac from record (identical bits)
    float4 r2 = rec[2], r3 = rec[3];
    float abx = r2.y, aby = r2.z, abz = r2.w;
    float acx = r3.x, acy = r3.y, acz = r3.z;
    float nx = (aby * acz) - (abz * acy);
    float ny = (abz * acx) - (abx * acz);
    float nz = (abx * acy) - (aby * acx);

    float dx = px - rx, dy = py - ry, dz = pz - rz;
    float sdot = ((dx * nx) + (dy * ny)) + (dz * nz);
    float sgn = (sdot >= 0.0f) ? 1.0f : -1.0f;
    float sdist = sgn * __fsqrt_rn(fmaxf(best_d2, 0.0f));

    out[q * 4 + 0] = rx;
    out[q * 4 + 1] = ry;
    out[q * 4 + 2] = rz;
    out[q * 4 + 3] = sdist;
}

extern "C" void kernel_launch(void* const* d_in, const int* in_sizes, int n_in,
                              void* d_out, int out_size, void* d_ws, size_t ws_size,
                              hipStream_t stream) {
    const int* faces = (const int*)d_in[0];
    const float* verts = (const float*)d_in[1];
    const float* query = (const float*)d_in[2];
    float* out = (float*)d_out;

    const int nF = in_sizes[0] / 3;
    const int nQ = in_sizes[2] / 3;

    unsigned long long* keys = (unsigned long long*)d_ws;
    float* tris = (float*)((char*)d_ws + (size_t)nQ * 8);

    int prep_threads = (nQ > nF ? nQ : nF);
    k_prep<<<(prep_threads + 255) / 256, 256, 0, stream>>>(faces, verts, tris, keys, nF, nQ);

    dim3 grid((nQ + QPB - 1) / QPB, (nF + FC - 1) / FC);
    k_main<<<grid, QPB, 0, stream>>>(tris, query, keys, nF, nQ);

    k_final<<<(nQ + 255) / 256, 256, 0, stream>>>(tris, query, keys, out, nQ);
}

// Round 6
// 126.575 us; speedup vs baseline: 1.0463x; 1.0049x over previous
//
#include <hip/hip_runtime.h>
#include <stdint.h>

// SDF closest-point + signed distance, 8192 queries x 2048 tris.
//
// Correctness model (verified R4/R5): harness ref = numpy float32 faithful
// chain. Requirements: strict IEEE f32, NO fma contraction (pragma inside
// every function body), numpy op order, np.argmin first-occurrence on f32 d2.
// Selection merge: u64 atomicMin on (d2bits<<32 | idx) == lexicographic
// (d2, idx) min == np.argmin first occurrence. Verified passing.
//
// R6 changes (perf only, arithmetic untouched):
//  - k_main reads face records straight from global with WAVE-UNIFORM
//    addresses (blockIdx/induction-derived) -> LLVM scalarizes to s_load,
//    face data lives in SGPRs, no LDS, no staging barrier.
//  - FC 64 -> 32, grid 2048 blocks -> nominal 32 waves/CU to hide divide
//    and scalar-load latency.

#define QPB 256   // queries per block (threads)
#define FC  32    // faces per chunk (one chunk per block.y)
#define RECF 20   // floats per face record (18 + pad)

__device__ __forceinline__ float safe32(float x) {
    return (fabsf(x) < 1e-12f) ? 1e-12f : x;
}

// Strict-f32 Ericson closest point, record layout: a3 b3 c3 ab3 ac3 cb3 pad2.
// Bit-identical to the numpy reference chain (region priority
// a > b > ab > c > ac > bc > interior via exclusive masks).
__device__ __forceinline__ float cp32(
    float px, float py, float pz, const float* __restrict__ t,
    float& rx, float& ry, float& rz)
{
#pragma clang fp contract(off)
    float ax  = t[0],  ay  = t[1],  az  = t[2];
    float bx  = t[3],  by  = t[4],  bz  = t[5];
    float cx  = t[6],  cy  = t[7],  cz  = t[8];
    float abx = t[9],  aby = t[10], abz = t[11];
    float acx = t[12], acy = t[13], acz = t[14];
    float cbx = t[15], cby = t[16], cbz = t[17];

    float apx = px - ax, apy = py - ay, apz = pz - az;
    float bpx = px - bx, bpy = py - by, bpz = pz - bz;
    float qpx = px - cx, qpy = py - cy, qpz = pz - cz;

    float d1 = ((abx * apx) + (aby * apy)) + (abz * apz);
    float d2 = ((acx * apx) + (acy * apy)) + (acz * apz);
    float d3 = ((abx * bpx) + (aby * bpy)) + (abz * bpz);
    float d4 = ((acx * bpx) + (acy * bpy)) + (acz * bpz);
    float d5 = ((abx * qpx) + (aby * qpy)) + (abz * qpz);
    float d6 = ((acx * qpx) + (acy * qpy)) + (acz * qpz);

    float vc = (d1 * d4) - (d3 * d2);
    float vb = (d5 * d2) - (d1 * d6);
    float va = (d3 * d6) - (d5 * d4);
    float e1 = d4 - d3;
    float e2 = d5 - d6;

    bool ca  = (d1 <= 0.0f) && (d2 <= 0.0f);
    bool cb_ = (d3 >= 0.0f) && (d4 <= d3);
    bool cab = (vc <= 0.0f) && (d1 >= 0.0f) && (d3 <= 0.0f);
    bool cc  = (d6 >= 0.0f) && (d5 <= d6);
    bool cac = (vb <= 0.0f) && (d2 >= 0.0f) && (d6 <= 0.0f);
    bool cbc = (va <= 0.0f) && (e1 >= 0.0f) && (e2 >= 0.0f);

    // priority a > b > ab > c > ac > bc > interior; exclusive masks
    bool tk  = ca;
    bool m_b  = cb_ && !tk;  tk = tk || cb_;
    bool m_ab = cab && !tk;  tk = tk || cab;
    bool m_c  = cc  && !tk;  tk = tk || cc;
    bool m_ac = cac && !tk;  tk = tk || cac;
    bool m_bc = cbc && !tk;  tk = tk || cbc;
    bool m_in = !tk;

    float denom_raw = (va + vb) + vc;
    float num1 = m_ab ? d1 : m_ac ? d2 : m_bc ? e1 : m_in ? vb : 0.0f;
    float den1_raw = m_ab ? (d1 - d3) : m_ac ? (d2 - d6)
                   : m_bc ? (e1 + e2) : m_in ? denom_raw : 1.0f;
    float den1  = safe32(den1_raw);
    float denom = safe32(denom_raw);
    float num2  = m_in ? vc : 0.0f;
    float q1 = num1 / den1;    // IEEE f32 divide
    float q2 = num2 / denom;

    bool sel_b = m_b || m_bc;
    float basx = m_c ? cx : sel_b ? bx : ax;
    float basy = m_c ? cy : sel_b ? by : ay;
    float basz = m_c ? cz : sel_b ? bz : az;

    bool s_ab = m_ab || m_in;
    float t1x = m_bc ? cbx : m_ac ? acx : s_ab ? abx : 0.0f;
    float t1y = m_bc ? cby : m_ac ? acy : s_ab ? aby : 0.0f;
    float t1z = m_bc ? cbz : m_ac ? acz : s_ab ? abz : 0.0f;

    float t2x = m_in ? acx : 0.0f;
    float t2y = m_in ? acy : 0.0f;
    float t2z = m_in ? acz : 0.0f;

    rx = (basx + (t1x * q1)) + (t2x * q2);
    ry = (basy + (t1y * q1)) + (t2y * q2);
    rz = (basz + (t1z * q1)) + (t2z * q2);

    float dx = px - rx, dy = py - ry, dz = pz - rz;
    return ((dx * dx) + (dy * dy)) + (dz * dz);
}

// Gather faces -> 20-float records (a,b,c,ab,ac,cb,pad2); init argmin keys.
__global__ void k_prep(const int* __restrict__ faces, const float* __restrict__ verts,
                       float* __restrict__ tris, unsigned long long* __restrict__ keys,
                       int nF, int nQ)
{
#pragma clang fp contract(off)
    int i = blockIdx.x * 256 + threadIdx.x;
    if (i < nQ) keys[i] = 0xffffffffffffffffULL;
    if (i < nF) {
        int i0 = faces[i * 3 + 0], i1 = faces[i * 3 + 1], i2 = faces[i * 3 + 2];
        float ax = verts[i0 * 3], ay = verts[i0 * 3 + 1], az = verts[i0 * 3 + 2];
        float bx = verts[i1 * 3], by = verts[i1 * 3 + 1], bz = verts[i1 * 3 + 2];
        float cx = verts[i2 * 3], cy = verts[i2 * 3 + 1], cz = verts[i2 * 3 + 2];
        float* t = &tris[i * RECF];
        t[0]  = ax; t[1]  = ay; t[2]  = az; t[3]  = bx;
        t[4]  = by; t[5]  = bz; t[6]  = cx; t[7]  = cy;
        t[8]  = cz;
        t[9]  = bx - ax; t[10] = by - ay; t[11] = bz - az;   // ab
        t[12] = cx - ax; t[13] = cy - ay; t[14] = cz - az;   // ac
        t[15] = cx - bx; t[16] = cy - by; t[17] = cz - bz;   // cb
        t[18] = 0.0f; t[19] = 0.0f;
    }
}

// Main: thread = one query, block = 32-face chunk. Face record address is
// wave-uniform -> scalar loads; face data in SGPRs. One u64 atomicMin per
// (query, chunk).
__global__ __launch_bounds__(QPB) void k_main(
    const float* __restrict__ tris, const float* __restrict__ query,
    unsigned long long* __restrict__ keys, int nF, int nQ)
{
    const int fbase = blockIdx.y * FC;
    const int nf = min(FC, nF - fbase);

    const int q = blockIdx.x * QPB + threadIdx.x;
    if (q >= nQ) return;
    const float px = query[q * 3], py = query[q * 3 + 1], pz = query[q * 3 + 2];

    float best = 3.402823466e38f;
    int bidx = 0x7fffffff;
#pragma unroll 2
    for (int f = 0; f < nf; ++f) {
        float rx, ry, rz;
        float d2 = cp32(px, py, pz, &tris[(size_t)(fbase + f) * RECF],
                        rx, ry, rz);
        // f ascends: strict < keeps lowest index on exact ties
        if (d2 < best) { best = d2; bidx = fbase + f; }
    }
    unsigned long long key =
        ((unsigned long long)__float_as_uint(best) << 32) | (unsigned)bidx;
    atomicMin(&keys[q], key);
}

// Finalize: decode winner, recompute cp (identical bits), normal, sign.
__global__ void k_final(const float* __restrict__ tris, const float* __restrict__ query,
                        const unsigned long long* __restrict__ keys,
                        float* __restrict__ out, int nQ)
{
#pragma clang fp contract(off)
    int q = blockIdx.x * 256 + threadIdx.x;
    if (q >= nQ) return;
    unsigned long long key = keys[q];
    unsigned idx = (unsigned)(key & 0xffffffffu);
    float best_d2 = __uint_as_float((unsigned)(key >> 32));

    const float px = query[q * 3], py = query[q * 3 + 1], pz = query[q * 3 + 2];
    const float* t = &tris[(size_t)idx * RECF];
    float rx, ry, rz;
    cp32(px, py, pz, t, rx, ry, rz);

    // n = cross(ab, ac), numpy order; ab/ac from record (identical bits)
    float abx = t[9],  aby = t[10], abz = t[11];
    float acx = t[12], acy = t[13], acz = t[14];
    float nx = (aby * acz) - (abz * acy);
    float ny = (abz * acx) - (abx * acz);
    float nz = (abx * acy) - (aby * acx);

    float dx = px - rx, dy = py - ry, dz = pz - rz;
    float sdot = ((dx * nx) + (dy * ny)) + (dz * nz);
    float sgn = (sdot >= 0.0f) ? 1.0f : -1.0f;
    float sdist = sgn * __fsqrt_rn(fmaxf(best_d2, 0.0f));

    out[q * 4 + 0] = rx;
    out[q * 4 + 1] = ry;
    out[q * 4 + 2] = rz;
    out[q * 4 + 3] = sdist;
}

extern "C" void kernel_launch(void* const* d_in, const int* in_sizes, int n_in,
                              void* d_out, int out_size, void* d_ws, size_t ws_size,
                              hipStream_t stream) {
    const int* faces = (const int*)d_in[0];
    const float* verts = (const float*)d_in[1];
    const float* query = (const float*)d_in[2];
    float* out = (float*)d_out;

    const int nF = in_sizes[0] / 3;
    const int nQ = in_sizes[2] / 3;

    unsigned long long* keys = (unsigned long long*)d_ws;
    float* tris = (float*)((char*)d_ws + (size_t)nQ * 8);

    int prep_threads = (nQ > nF ? nQ : nF);
    k_prep<<<(prep_threads + 255) / 256, 256, 0, stream>>>(faces, verts, tris, keys, nF, nQ);

    dim3 grid((nQ + QPB - 1) / QPB, (nF + FC - 1) / FC);
    k_main<<<grid, QPB, 0, stream>>>(tris, query, keys, nF, nQ);

    k_final<<<(nQ + 255) / 256, 256, 0, stream>>>(tris, query, keys, out, nQ);
}